// Round 5
// baseline (279.089 us; speedup 1.0000x reference)
//
#include <hip/hip_runtime.h>
#include <math.h>

// B=4, H=256, W=256, 100 iters. Closed-form update (3-pt GH quadrature is
// exact for these degree<=4 integrands; log/NDC terms cancel):
//   dmu  = 2*uw1*mu + uw2*y + sum_edges ew*mu_nb
//   dsg  = 2*uw1*sg + sum_edges ew*rou_edge*sg_nb
//   drou = ew*sg_self*sg_nb        (per owned edge)
// Temporal blocking: T=10 iters/launch, 54x52 tile (halo 11 rows/10 cols),
// 256 blocks (1/CU), double-buffered LDS, 1 barrier/iter.
// Round 13: revert r12's T=16 (halo work (32+2T)^2 beats 1/T amortization;
// +21us matched +DS-work -> per-launch overhead is ~1-2us, DS pipe is the
// controllable bound). 2x2 px patch per thread: 8 reads + 4 writes / 4 px
// = 3.0 DS/px vs 3.67 (strip). 27x26=702 active threads (11 waves, above
// the ~10.6-wave plateau, no r11 occupancy cliff). Shrinking gate in BOTH
// dims: need(s+1) = rows[2+s,51-s] x cols[1+s,50-s]; px-iter 224640 ->
// 171400. Gates are exact need-membership: every unmasked px's neighbors
// were unmasked the previous step (need shrinks by 1-dilation/step); stale
// values finite, never read by live px. Global loads now flat cooperative
// (stage st->buf0, c1->buf1, v->buf1) so patch layout doesn't de-coalesce
// them; k2 comes from staged c1 plane (ews trick retired).
#define NPIX  262144
#define NEDGE 524288
#define T     10
#define TILE_R 54
#define TILE_C 52
#define TS     53            // padded LDS row stride (float4 units)
#define NPLANE (TILE_R*TILE_C)   // 2808
#define NRG   27             // 2-row groups
#define NCG   26             // 2-col groups
#define ACTIVE (NRG*NCG)     // 702 active threads of 768
#define NTHR  768
#define HALO_R 11
#define HALO_C 10

__device__ __forceinline__ float clampf(float x, float lo, float hi) {
    return fminf(fmaxf(x, lo), hi);
}

// State float4 {mu, sigma, rou0(down-edge), rou1(right-edge)}.
// c1 = {2*uw1, uw2*y, ew0, ew1}.
__global__ __launch_bounds__(NTHR) void tile_kernel(
    const float4* __restrict__ stI, const float4* __restrict__ vI,
    float4* __restrict__ stO, float4* __restrict__ vO,
    const float4* __restrict__ c1,
    float* __restrict__ mu_out,   // non-null on last launch (st/v not stored)
    int first)                    // launch 0: v := 0, vI not read
{
    __shared__ float4 buf[2][TILE_R*TS];   // 91.6 KB

    int tid = threadIdx.x;
    int rg  = tid / NCG;
    int cg  = tid - rg*NCG;
    bool act = (tid < ACTIVE);
    int bz = blockIdx.z;
    int h0 = blockIdx.y * 32;
    int w0 = blockIdx.x * 32;
    int r0 = 2*rg, c0 = 2*cg;

    float4 st[2][2], v[2][2], k1[2][2];
    float k2x[2], k2y[2];
    int hh[2], ww[2];

    // ---- coop flat load: st -> buf0, c1 -> buf1 (fully coalesced rows) ----
    float4* stg = buf[1];
    for (int f = tid; f < NPLANE; f += NTHR) {
        int r = f / TILE_C, c = f - r*TILE_C;
        int h  = (h0 + r - HALO_R) & 255;
        int wv = (w0 + c - HALO_C) & 255;
        int g = (bz << 16) | (h << 8) | wv;
        buf[0][r*TS + c] = stI[g];
        stg[r*TS + c]    = c1[g];
    }
    __syncthreads();

    // extract patch st/k1 + boundary neighbor ew from staged c1.
    // Clamped at tile edge -> finite garbage; edge px are garbage-region.
    if (act) {
#pragma unroll
        for (int i = 0; i < 2; ++i) hh[i] = (h0 + r0 + i - HALO_R) & 255;
#pragma unroll
        for (int j = 0; j < 2; ++j) ww[j] = (w0 + c0 + j - HALO_C) & 255;
#pragma unroll
        for (int i = 0; i < 2; ++i)
#pragma unroll
            for (int j = 0; j < 2; ++j) {
                st[i][j] = buf[0][(r0+i)*TS + c0+j];
                k1[i][j] = stg[(r0+i)*TS + c0+j];
            }
        int ru = (r0 == 0) ? 0 : r0-1;
        int cl = (c0 == 0) ? 0 : c0-1;
#pragma unroll
        for (int j = 0; j < 2; ++j)
            k2x[j] = ((const float*)&stg[ru*TS + c0+j])[2];   // up-nb ew0
#pragma unroll
        for (int i = 0; i < 2; ++i)
            k2y[i] = ((const float*)&stg[(r0+i)*TS + cl])[3]; // left-nb ew1
    }
    __syncthreads();   // k1/k2 extracted before v overwrites stg

    // ---- v plane through the same staging buffer ----
    if (!first) {
        for (int f = tid; f < NPLANE; f += NTHR) {
            int r = f / TILE_C, c = f - r*TILE_C;
            int h  = (h0 + r - HALO_R) & 255;
            int wv = (w0 + c - HALO_C) & 255;
            int g = (bz << 16) | (h << 8) | wv;
            stg[r*TS + c] = vI[g];
        }
    }
    __syncthreads();
    if (act) {
#pragma unroll
        for (int i = 0; i < 2; ++i)
#pragma unroll
            for (int j = 0; j < 2; ++j)
                v[i][j] = first ? make_float4(0.f, 0.f, 0.f, 0.f)
                                : stg[(r0+i)*TS + c0+j];
    }
    __syncthreads();   // v extracted before iter 0 writes buf1

    // ---- T fused Jacobi iterations, one barrier each, 2D shrinking gate ----
    for (int s = 0; s < T; ++s) {
        const float4* __restrict__ cur = buf[s & 1];
        float4*       __restrict__ nxt = buf[(s & 1) ^ 1];
        int rLo = 2+s, rHi = 51-s;     // rows of need(s+1)
        int cLo = 1+s, cHi = 50-s;     // cols of need(s+1)
        bool ta = act && (r0+1 >= rLo) && (r0 <= rHi)
                      && (c0+1 >= cLo) && (c0 <= cHi);
        if (ta) {
            int rup = (r0 == 0)        ? 0        : r0-1;
            int rdn = (r0 == TILE_R-2) ? TILE_R-1 : r0+2;
            int clf = (c0 == 0)        ? 0        : c0-1;
            int crt = (c0 == TILE_C-2) ? TILE_C-1 : c0+2;
            float4 up[2], dn[2], lf[2], rt[2];
#pragma unroll
            for (int j = 0; j < 2; ++j) {
                up[j] = cur[rup*TS + c0+j];
                dn[j] = cur[rdn*TS + c0+j];
            }
#pragma unroll
            for (int i = 0; i < 2; ++i) {
                lf[i] = cur[(r0+i)*TS + clf];
                rt[i] = cur[(r0+i)*TS + crt];
            }
            float4 ns[2][2];
#pragma unroll
            for (int i = 0; i < 2; ++i) {
#pragma unroll
                for (int j = 0; j < 2; ++j) {
                    float4 U = (i == 0) ? up[j] : st[0][j];
                    float4 D = (i == 1) ? dn[j] : st[1][j];
                    float4 L = (j == 0) ? lf[i] : st[i][0];
                    float4 R = (j == 1) ? rt[i] : st[i][1];
                    float4 S = st[i][j];
                    float4 K = k1[i][j];
                    float K2x = (i == 0) ? k2x[j] : k1[0][j].z;
                    float K2y = (j == 0) ? k2y[i] : k1[i][0].w;
                    float dmu = K.x*S.x + K.y + K.z*D.x + K.w*R.x
                              + K2x*U.x + K2y*L.x;
                    float dsg = K.x*S.y + K.z*S.z*D.y + K.w*S.w*R.y
                              + K2x*U.z*U.y + K2y*L.w*L.y;
                    float dr0 = K.z*S.y*D.y;
                    float dr1 = K.w*S.y*R.y;
                    float4 V = v[i][j];
                    V.x = 0.7f*V.x + 0.01f*dmu;
                    V.y = 0.7f*V.y + 0.01f*dsg;
                    V.z = 0.7f*V.z + 0.01f*dr0;
                    V.w = 0.7f*V.w + 0.01f*dr1;
                    v[i][j] = V;
                    float4 o;
                    o.x = clampf(S.x + V.x, 0.f, 63.f);
                    o.y = clampf(S.y + V.y, 0.001f, 50.f);
                    o.z = clampf(S.z + V.z, -0.99f, 0.99f);
                    o.w = clampf(S.w + V.w, -0.99f, 0.99f);
                    ns[i][j] = o;
                }
            }
#pragma unroll
            for (int i = 0; i < 2; ++i)
#pragma unroll
                for (int j = 0; j < 2; ++j) {
                    st[i][j] = ns[i][j];
                    int r = r0+i, c = c0+j;
                    if (r >= rLo && r <= rHi && c >= cLo && c <= cHi)
                        nxt[r*TS + c] = ns[i][j];   // write only need(s+1)
                }
        }
        __syncthreads();   // all reads of cur done AND nxt fully written
    }

    // ---- store interior (rows [HALO_R, +32), cols [HALO_C, +32)) ----
    if (act) {
#pragma unroll
        for (int i = 0; i < 2; ++i)
#pragma unroll
            for (int j = 0; j < 2; ++j) {
                int r = r0+i, c = c0+j;
                if (r >= HALO_R && r < HALO_R+32 &&
                    c >= HALO_C && c < HALO_C+32) {
                    int g = (bz << 16) | (hh[i] << 8) | ww[j];
                    if (mu_out) {
                        mu_out[g] = st[i][j].x;   // final launch: only mu
                    } else {
                        stO[g] = st[i][j];
                        vO[g]  = v[i][j];
                    }
                }
            }
    }
}

// ---- global max(edge_weight); gmax pre-zeroed via hipMemsetAsync ----
// (0u is the order-preserving encoding of the most-negative float)
__global__ void reduce_max_kernel(const float* __restrict__ ew, unsigned int* gmax) {
    int i = blockIdx.x*blockDim.x + threadIdx.x;
    float m = -INFINITY;
    for (; i < NEDGE; i += gridDim.x*blockDim.x) m = fmaxf(m, ew[i]);
#pragma unroll
    for (int off = 32; off > 0; off >>= 1)
        m = fmaxf(m, __shfl_down(m, off, 64));
    if ((threadIdx.x & 63) == 0) {
        unsigned u = __float_as_uint(m);
        unsigned key = (u & 0x80000000u) ? ~u : (u | 0x80000000u);
        atomicMax(gmax, key);
    }
}

// init state + invariant coefficient plane (no v plane)
__global__ __launch_bounds__(256) void init_state_kernel(
    const float*  __restrict__ y,
    const float2* __restrict__ ew,
    const float2* __restrict__ uw,
    const unsigned int* __restrict__ gmax_enc,
    float4* stA, float4* c1)
{
    int idx = blockIdx.x*256 + threadIdx.x;

    unsigned key = *gmax_enc;
    unsigned u = (key & 0x80000000u) ? (key ^ 0x80000000u) : ~key;
    float gmax = __uint_as_float(u);
    float inv_denom = 1.f / (gmax*1.01f + 1.f);   // one-time, IEEE div fine

    float2 e   = ew[idx];
    float2 uwv = uw[idx];
    float  yv  = y[idx];
    float4 st;
    st.x = yv;
    st.y = 1.f;
    st.z = e.x * inv_denom;
    st.w = e.y * inv_denom;
    stA[idx] = st;
    c1[idx]  = make_float4(2.f*uwv.x, uwv.y*yv, e.x, e.y);
}

extern "C" void kernel_launch(void* const* d_in, const int* in_sizes, int n_in,
                              void* d_out, int out_size, void* d_ws, size_t ws_size,
                              hipStream_t stream) {
    const float* y  = (const float*)d_in[0];
    const float* ew = (const float*)d_in[1];
    const float* uw = (const float*)d_in[2];
    float* out = (float*)d_out;
    const int N = NPIX;

    // workspace: stA, stB, vA, vB, c1 (float4 planes) + 1 uint (~21 MB)
    float4* stA = (float4*)d_ws;
    float4* stB = stA + N;
    float4* vA  = stB + N;
    float4* vB  = vA + N;
    float4* c1  = vB + N;
    unsigned int* gmax = (unsigned int*)(c1 + N);

    hipMemsetAsync(gmax, 0, sizeof(unsigned int), stream);
    hipLaunchKernelGGL(reduce_max_kernel, dim3(512), dim3(256), 0, stream, ew, gmax);
    hipLaunchKernelGGL(init_state_kernel, dim3(N/256), dim3(256), 0, stream,
                       y, (const float2*)ew, (const float2*)uw, gmax,
                       stA, c1);

    float4 *stI = stA, *stO = stB, *vI = vA, *vO = vB;
    const int NLAUNCH = 100 / T;   // 10
    for (int l = 0; l < NLAUNCH; ++l) {
        float* mo = (l == NLAUNCH-1) ? out : nullptr;
        hipLaunchKernelGGL(tile_kernel, dim3(8, 8, 4), dim3(NTHR), 0, stream,
                           stI, vI, stO, vO, c1, mo, (l == 0) ? 1 : 0);
        float4* t;
        t = stI; stI = stO; stO = t;
        t = vI;  vI  = vO;  vO  = t;
    }
}

// Round 6
// 151.688 us; speedup vs baseline: 1.8399x; 1.8399x over previous
//
#include <hip/hip_runtime.h>
#include <math.h>

// B=4, H=256, W=256, 100 iters. Closed-form update (3-pt GH quadrature is
// exact for these degree<=4 integrands; log/NDC terms cancel):
//   dmu  = 2*uw1*mu + uw2*y + sum_edges ew*mu_nb   (mu-only 5-pt stencil!)
//   dsg, drou: computed by the reference but NEVER feed mu, and the output
//   is mu[...,0,0] only -> sigma/rou/v_sg/v_rou are dead code. Deleted.
// Round 14: mu-only state. LDS plane = 1 float/px (b32 stride-1, 2
// lanes/bank = free). Per thread-iter DS: 11 x b32 (~64 cyc) vs 11 x b128
// (~132) -> DS-pipe cycles halve (r2/r5 established time moves 1:1 with
// DS-pipe cycles). mu arithmetic chain expression-identical to the r2
// kernel -> same output. k2 boundary coeffs read directly from global c1
// (clamped); ews staging plane + one barrier retired. LDS 22.9 KB.
// Temporal blocking: T=10 iters/launch, 54x52 tile (halo 11 rows/10 cols),
// 256 blocks (1/CU), double-buffered LDS, 1 barrier/iter, shrinking row
// gate (rows [2+s, 51-s]; stored rows 11..42 = rowgroups 3..14 stay live).
#define NPIX  262144
#define NEDGE 524288
#define T     10
#define TILE_R 54
#define TILE_C 52
#define TS     53            // padded LDS row stride (floats)
#define RPT    3
#define NRG    18            // 18*3 = 54 exact
#define ACTIVE (TILE_C*NRG)  // 936 active threads of 1024
#define NTHR   1024
#define HALO_R 11
#define HALO_C 10

__device__ __forceinline__ float clampf(float x, float lo, float hi) {
    return fminf(fmaxf(x, lo), hi);
}

// c1 = {2*uw1, uw2*y, ew0(down-edge), ew1(right-edge)}.
__global__ __launch_bounds__(NTHR) void tile_kernel(
    const float* __restrict__ muI, const float* __restrict__ vI,
    float* __restrict__ muO, float* __restrict__ vO,
    const float4* __restrict__ c1,
    float* __restrict__ mu_out,   // non-null on last launch (mu/v not stored)
    int first)                    // launch 0: v := 0, vI not read
{
    __shared__ float buf[2][TILE_R*TS];   // 22.9 KB

    int tid = threadIdx.x;
    int rg  = tid / TILE_C;
    int col = tid - rg*TILE_C;
    bool act = (tid < ACTIVE);
    int bz = blockIdx.z;
    int h0 = blockIdx.y * 32;
    int w0 = blockIdx.x * 32;
    int w  = (w0 + col - HALO_C) & 255;
    int r0 = RPT*rg;

    float mu[RPT], v[RPT];
    float4 k1[RPT];
    float k2x0;          // up-nb ew0 for k=0 (k>0 uses k1[k-1].z)
    float k2y[RPT];      // left-nb ew1 per row
    int hh[RPT];

    // ---- load strip: mu -> LDS buf0 + regs; coeffs -> regs ----
    if (act) {
#pragma unroll
        for (int k = 0; k < RPT; ++k) {
            int r = r0 + k;
            int h = (h0 + r - HALO_R) & 255;
            hh[k] = h;
            int g = (bz << 16) | (h << 8) | w;
            float m = muI[g];
            mu[k] = m;
            buf[0][r*TS + col] = m;
            k1[k] = c1[g];
            v[k] = first ? 0.f : vI[g];
        }
        // boundary neighbor coeffs straight from global (clamped at tile
        // edge -> finite garbage; edge px are garbage-region by validity)
        int hu = (h0 + ((r0 == 0) ? 0 : r0-1) - HALO_R) & 255;
        k2x0 = c1[(bz << 16) | (hu << 8) | w].z;
        int wl = (w0 + ((col == 0) ? 0 : col-1) - HALO_C) & 255;
#pragma unroll
        for (int k = 0; k < RPT; ++k)
            k2y[k] = c1[(bz << 16) | (hh[k] << 8) | wl].w;
    }
    __syncthreads();

    // ---- T fused Jacobi iterations, one barrier each, shrinking gate ----
    int cl = (col == 0)        ? 0        : col-1;
    int cr = (col == TILE_C-1) ? TILE_C-1 : col+1;
    for (int s = 0; s < T; ++s) {
        const float* __restrict__ cur = buf[s & 1];
        float*       __restrict__ nxt = buf[(s & 1) ^ 1];
        int rgLo = (s + 2) / 3;      // useful rows [2+s, 51-s]
        int rgHi = (51 - s) / 3;
        if (act && rg >= rgLo && rg <= rgHi) {
            float nmu[RPT];
            float up0 = cur[((rg == 0)     ? 0          : (r0-1))*TS + col];
            float dnL = cur[((rg == NRG-1) ? (TILE_R-1) : (r0+RPT))*TS + col];
#pragma unroll
            for (int k = 0; k < RPT; ++k) {
                int r = r0 + k;
                float lf = cur[r*TS + cl];
                float rt = cur[r*TS + cr];
                float up = (k == 0)     ? up0 : mu[k-1];
                float dn = (k == RPT-1) ? dnL : mu[k+1];
                float4 K = k1[k];
                float K2x = (k == 0) ? k2x0 : k1[k-1].z;
                float dmu = K.x*mu[k] + K.y + K.z*dn + K.w*rt
                          + K2x*up + k2y[k]*lf;
                v[k] = 0.7f*v[k] + 0.01f*dmu;
                nmu[k] = clampf(mu[k] + v[k], 0.f, 63.f);
            }
#pragma unroll
            for (int k = 0; k < RPT; ++k) {
                mu[k] = nmu[k];
                nxt[(r0 + k)*TS + col] = nmu[k];
            }
        }
        __syncthreads();   // all reads of cur done AND nxt fully written
    }

    // ---- store interior (rows [HALO_R, +32), cols [HALO_C, +32)) ----
    if (act && col >= HALO_C && col < HALO_C+32) {
#pragma unroll
        for (int k = 0; k < RPT; ++k) {
            int r = r0 + k;
            if (r >= HALO_R && r < HALO_R+32) {
                int g = (bz << 16) | (hh[k] << 8) | w;
                if (mu_out) {
                    mu_out[g] = mu[k];       // final launch: only mu needed
                } else {
                    muO[g] = mu[k];
                    vO[g]  = v[k];
                }
            }
        }
    }
}

// ---- global max(edge_weight); gmax pre-zeroed via hipMemsetAsync ----
// (0u is the order-preserving encoding of the most-negative float)
__global__ void reduce_max_kernel(const float* __restrict__ ew, unsigned int* gmax) {
    int i = blockIdx.x*blockDim.x + threadIdx.x;
    float m = -INFINITY;
    for (; i < NEDGE; i += gridDim.x*blockDim.x) m = fmaxf(m, ew[i]);
#pragma unroll
    for (int off = 32; off > 0; off >>= 1)
        m = fmaxf(m, __shfl_down(m, off, 64));
    if ((threadIdx.x & 63) == 0) {
        unsigned u = __float_as_uint(m);
        unsigned key = (u & 0x80000000u) ? ~u : (u | 0x80000000u);
        atomicMax(gmax, key);
    }
}

// init mu plane + invariant coefficient plane
// (gmax kept for exact parity with the reference's rou init, even though
//  rou no longer feeds the output path — c1 itself doesn't use it)
__global__ __launch_bounds__(256) void init_state_kernel(
    const float*  __restrict__ y,
    const float2* __restrict__ ew,
    const float2* __restrict__ uw,
    float* muA, float4* c1)
{
    int idx = blockIdx.x*256 + threadIdx.x;
    float2 e   = ew[idx];
    float2 uwv = uw[idx];
    float  yv  = y[idx];
    muA[idx] = yv;
    c1[idx]  = make_float4(2.f*uwv.x, uwv.y*yv, e.x, e.y);
}

extern "C" void kernel_launch(void* const* d_in, const int* in_sizes, int n_in,
                              void* d_out, int out_size, void* d_ws, size_t ws_size,
                              hipStream_t stream) {
    const float* y  = (const float*)d_in[0];
    const float* ew = (const float*)d_in[1];
    const float* uw = (const float*)d_in[2];
    float* out = (float*)d_out;
    const int N = NPIX;

    // workspace: c1 (float4 plane) + muA, muB, vA, vB (float planes) ~8 MB
    float4* c1  = (float4*)d_ws;
    float*  muA = (float*)(c1 + N);
    float*  muB = muA + N;
    float*  vA  = muB + N;
    float*  vB  = vA + N;

    hipLaunchKernelGGL(init_state_kernel, dim3(N/256), dim3(256), 0, stream,
                       y, (const float2*)ew, (const float2*)uw, muA, c1);

    float *muI = muA, *muO = muB, *vI = vA, *vO = vB;
    const int NLAUNCH = 100 / T;   // 10
    for (int l = 0; l < NLAUNCH; ++l) {
        float* mo = (l == NLAUNCH-1) ? out : nullptr;
        hipLaunchKernelGGL(tile_kernel, dim3(8, 8, 4), dim3(NTHR), 0, stream,
                           muI, vI, muO, vO, c1, mo, (l == 0) ? 1 : 0);
        float* t;
        t = muI; muI = muO; muO = t;
        t = vI;  vI  = vO;  vO  = t;
    }
}